// Round 4
// baseline (504.626 us; speedup 1.0000x reference)
//
#include <hip/hip_runtime.h>
#include <hip/hip_bf16.h>
#include <math.h>

#define B1 2048
#define B2 8192
#define NH 12
#define DH 64
#define DMODEL 768

typedef __attribute__((ext_vector_type(8))) short short8;
typedef __attribute__((ext_vector_type(4))) float floatx4;
typedef __attribute__((ext_vector_type(16))) float floatx16;
typedef __attribute__((ext_vector_type(8))) unsigned short ushort8;
typedef __attribute__((ext_vector_type(4))) unsigned short ushort4v;
typedef __attribute__((ext_vector_type(4))) unsigned int uintx4;

static __device__ __forceinline__ unsigned short f2bf(float f) {
  __bf16 b = (__bf16)f;
  return __builtin_bit_cast(unsigned short, b);
}
static __device__ __forceinline__ float bf2f(unsigned short u) {
  return __builtin_bit_cast(float, ((unsigned)u) << 16);
}

// async global->LDS, 16B per lane; LDS dest = wave-uniform base + lane*16
static __device__ __forceinline__ void gload16(const unsigned short* g,
                                               unsigned short* l) {
  __builtin_amdgcn_global_load_lds(
      (const __attribute__((address_space(1))) void*)g,
      (__attribute__((address_space(3))) void*)l, 16, 0, 0);
}

// ---------------------------------------------------------------------------
// Fused prep: ALL fp32 -> bf16 hi/lo splits + hi-only converts, one launch.
// block-role table: [0,1536) x1 | [1536,7680) x2 | [7680,8256) Wq |
// [8256,8832) Wk | [8832,9408) Wv(hi only) | [9408,9984) Wo(hi only)
// ---------------------------------------------------------------------------
__global__ __launch_bounds__(256) void prep_all(
    const float* __restrict__ x1, unsigned short* __restrict__ x1h,
    unsigned short* __restrict__ x1l, const float* __restrict__ x2,
    unsigned short* __restrict__ x2h, unsigned short* __restrict__ x2l,
    const float* __restrict__ Wq, unsigned short* __restrict__ Wqh,
    unsigned short* __restrict__ Wql, const float* __restrict__ Wk,
    unsigned short* __restrict__ Wkh, unsigned short* __restrict__ Wkl,
    const float* __restrict__ Wv, unsigned short* __restrict__ Wvh,
    const float* __restrict__ Wo, unsigned short* __restrict__ Woh) {
  const int bi = blockIdx.x;
  const float* src;
  unsigned short *hi, *lo = nullptr;
  int lb;
  if (bi < 1536) {
    src = x1; hi = x1h; lo = x1l; lb = bi;
  } else if (bi < 7680) {
    src = x2; hi = x2h; lo = x2l; lb = bi - 1536;
  } else if (bi < 8256) {
    src = Wq; hi = Wqh; lo = Wql; lb = bi - 7680;
  } else if (bi < 8832) {
    src = Wk; hi = Wkh; lo = Wkl; lb = bi - 8256;
  } else if (bi < 9408) {
    src = Wv; hi = Wvh; lb = bi - 8832;
  } else {
    src = Wo; hi = Woh; lb = bi - 9408;
  }
  const int i = (lb * 256 + threadIdx.x) * 4;
  const float4 v = *(const float4*)&src[i];
  ushort4v h = {f2bf(v.x), f2bf(v.y), f2bf(v.z), f2bf(v.w)};
  *(ushort4v*)&hi[i] = h;
  if (lo) {
    ushort4v l = {f2bf(v.x - bf2f(h[0])), f2bf(v.y - bf2f(h[1])),
                  f2bf(v.z - bf2f(h[2])), f2bf(v.w - bf2f(h[3]))};
    *(ushort4v*)&lo[i] = l;
  }
}

// ---------------------------------------------------------------------------
// Core bf16 MFMA GEMM tile: C[M,N] = A[M,K]*B[N,K]^T (both K-contiguous).
// 128x128 tile, BK=32, 4 waves (2x2), 64x64/wave, global_load_lds staging,
// XOR-swizzled granules (swizzle on GLOBAL addr; frag reads 2-way = free).
// SPLIT: hi/lo 3-MFMA k-step (~fp32). L2N: per-64-col L2 norm epilogue.
// ---------------------------------------------------------------------------
template <bool SPLIT, bool L2N, bool F32OUT>
static __device__ __forceinline__ void gemm_tile(
    const unsigned short* __restrict__ Ahg, const unsigned short* __restrict__ Alg,
    const unsigned short* __restrict__ Bhg, const unsigned short* __restrict__ Blg,
    void* __restrict__ Cv, int M, int N, int K, int m0, int n0,
    unsigned short* sAh, unsigned short* sBh, unsigned short* sAl,
    unsigned short* sBl) {
  const int tid = threadIdx.x;
  const int wave = tid >> 6;
  const int lane = tid & 63;
  const int wm = wave >> 1;
  const int wn = wave & 1;
  const int n15 = lane & 15;
  const int quad = lane >> 4;
  const int srow = lane >> 2;
  const int cpl = (lane & 3) ^ (srow >> 2);

  floatx4 acc[4][4];
#pragma unroll
  for (int i = 0; i < 4; ++i)
#pragma unroll
    for (int j = 0; j < 4; ++j) acc[i][j] = (floatx4){0.f, 0.f, 0.f, 0.f};

  for (int k0 = 0; k0 < K; k0 += 32) {
    __syncthreads();
#pragma unroll
    for (int jj = 0; jj < 2; ++jj) {
      const int j = wave * 2 + jj;
      const int row = j * 16 + srow;
      const size_t goffA = (size_t)(m0 + row) * K + k0 + cpl * 8;
      const size_t goffB = (size_t)(n0 + row) * K + k0 + cpl * 8;
      gload16(Ahg + goffA, &sAh[j * 512]);
      gload16(Bhg + goffB, &sBh[j * 512]);
      if constexpr (SPLIT) {
        gload16(Alg + goffA, &sAl[j * 512]);
        gload16(Blg + goffB, &sBl[j * 512]);
      }
    }
    __syncthreads();

    short8 afh[4], afl[4];
#pragma unroll
    for (int mt = 0; mt < 4; ++mt) {
      const int row = wm * 64 + mt * 16 + n15;
      const int off = row * 32 + ((quad ^ (n15 >> 2)) << 3);
      afh[mt] = *(const short8*)&sAh[off];
      if constexpr (SPLIT) afl[mt] = *(const short8*)&sAl[off];
    }
#pragma unroll
    for (int nt = 0; nt < 4; ++nt) {
      const int row = wn * 64 + nt * 16 + n15;
      const int off = row * 32 + ((quad ^ (n15 >> 2)) << 3);
      const short8 bfh = *(const short8*)&sBh[off];
      if constexpr (SPLIT) {
        const short8 bfl = *(const short8*)&sBl[off];
#pragma unroll
        for (int mt = 0; mt < 4; ++mt) {
          acc[mt][nt] = __builtin_amdgcn_mfma_f32_16x16x32_bf16(afh[mt], bfh, acc[mt][nt], 0, 0, 0);
          acc[mt][nt] = __builtin_amdgcn_mfma_f32_16x16x32_bf16(afh[mt], bfl, acc[mt][nt], 0, 0, 0);
          acc[mt][nt] = __builtin_amdgcn_mfma_f32_16x16x32_bf16(afl[mt], bfh, acc[mt][nt], 0, 0, 0);
        }
      } else {
#pragma unroll
        for (int mt = 0; mt < 4; ++mt)
          acc[mt][nt] = __builtin_amdgcn_mfma_f32_16x16x32_bf16(afh[mt], bfh, acc[mt][nt], 0, 0, 0);
      }
    }
  }

#pragma unroll
  for (int mt = 0; mt < 4; ++mt) {
    float scalev[4] = {1.f, 1.f, 1.f, 1.f};
    if constexpr (L2N) {
#pragma unroll
      for (int rr = 0; rr < 4; ++rr) {
        float ss = 0.f;
#pragma unroll
        for (int nt = 0; nt < 4; ++nt) ss += acc[mt][nt][rr] * acc[mt][nt][rr];
        ss += __shfl_xor(ss, 1, 64);
        ss += __shfl_xor(ss, 2, 64);
        ss += __shfl_xor(ss, 4, 64);
        ss += __shfl_xor(ss, 8, 64);
        scalev[rr] = 1.0f / fmaxf(sqrtf(ss), 1e-12f);
      }
    }
#pragma unroll
    for (int nt = 0; nt < 4; ++nt) {
#pragma unroll
      for (int rr = 0; rr < 4; ++rr) {
        const int row = m0 + wm * 64 + mt * 16 + quad * 4 + rr;
        const int col = n0 + wn * 64 + nt * 16 + n15;
        const float v = acc[mt][nt][rr] * scalev[rr];
        if constexpr (F32OUT)
          ((float*)Cv)[(size_t)row * N + col] = v;
        else
          ((unsigned short*)Cv)[(size_t)row * N + col] = f2bf(v);
      }
    }
  }
}

// ---------------------------------------------------------------------------
// Fused q-proj + k-proj (both SPLIT + per-head L2N, bf16 out). 480 blocks.
// ---------------------------------------------------------------------------
__global__ __launch_bounds__(256) void qk_proj(
    const unsigned short* __restrict__ x1h, const unsigned short* __restrict__ x1l,
    const unsigned short* __restrict__ Wqh, const unsigned short* __restrict__ Wql,
    const unsigned short* __restrict__ x2h, const unsigned short* __restrict__ x2l,
    const unsigned short* __restrict__ Wkh, const unsigned short* __restrict__ Wkl,
    unsigned short* __restrict__ qbf, unsigned short* __restrict__ kbf) {
  __shared__ __align__(16) unsigned short sAh[4096], sBh[4096], sAl[4096], sBl[4096];
  const int bi = blockIdx.x;
  if (bi < 96) {
    gemm_tile<true, true, false>(x1h, x1l, Wqh, Wql, qbf, B1, DMODEL, DMODEL,
                                 (bi / 6) * 128, (bi % 6) * 128, sAh, sBh, sAl, sBl);
  } else {
    const int b = bi - 96;
    gemm_tile<true, true, false>(x2h, x2l, Wkh, Wkl, kbf, B2, DMODEL, DMODEL,
                                 (b / 6) * 128, (b % 6) * 128, sAh, sBh, sAl, sBl);
  }
}

// ---------------------------------------------------------------------------
// Fused v-proj (vt = Wv @ x2^T, plain bf16) + zero aoacc + zero lacc.
// roles: [0,384) v-proj | [384,768) zero aoacc | [768,774) zero lacc.
// ---------------------------------------------------------------------------
__global__ __launch_bounds__(256) void v_zero(
    const unsigned short* __restrict__ Wvh, const unsigned short* __restrict__ x2h,
    unsigned short* __restrict__ vtbf, float* __restrict__ aoacc,
    float* __restrict__ lacc) {
  __shared__ __align__(16) unsigned short sAh[4096], sBh[4096];
  const int bi = blockIdx.x;
  if (bi < 384) {
    gemm_tile<false, false, false>(Wvh, nullptr, x2h, nullptr, vtbf, DMODEL, B2,
                                   DMODEL, (bi / 64) * 128, (bi % 64) * 128,
                                   sAh, sBh, nullptr, nullptr);
  } else if (bi < 768) {
    const float4 z = {0.f, 0.f, 0.f, 0.f};
    float4* p = (float4*)aoacc + (size_t)(bi - 384) * 1024 + threadIdx.x;
    p[0] = z; p[256] = z; p[512] = z; p[768] = z;
  } else {
    const float4 z = {0.f, 0.f, 0.f, 0.f};
    float4* p = (float4*)lacc + (size_t)(bi - 768) * 1024 + threadIdx.x;
    p[0] = z; p[256] = z; p[512] = z; p[768] = z;
  }
}

// ---------------------------------------------------------------------------
// MFMA bf16 attention, 32x32x16, NATURAL-ORDER PV (no cross-lane exchange):
//  - QK^T per wave: S[32 key][32 q] via mfma(kf, qf); D col = q = lane&31.
//  - softmax in-register; pk[0..3]/pk[4..7] ARE the PV A-frags under the
//    k-slot<->key bijection  key(hi,j) = 16p + (j<4 ? 4hi+j : 8+4hi+j-4).
//    V B-frag = two 8B half-granule reads matching that key order.
//  - LDS = Kl(16K) + Vl(16K) = 32 KiB.
//  - KSPLIT=2 (atomic traffic back to R0 level). Grid 768.
// Wave map: qsub = wave>>1 (32 q rows), ksub = wave&1 (64 of 128 chunk keys).
// ---------------------------------------------------------------------------
#define KC 128
#define KSPLIT 2
#define NCH (B2 / KSPLIT / KC)  // 32

__global__ __launch_bounds__(256, 4) void attn_mfma(
    const unsigned short* __restrict__ qb, const unsigned short* __restrict__ kb,
    const unsigned short* __restrict__ vt, float* __restrict__ aoacc,
    float* __restrict__ lacc, const int* __restrict__ invt_p) {
  __shared__ __align__(16) unsigned short smem[16384];  // 32768 B
  unsigned short* Kl = smem;         // [128 keys][64 dims], swizzled granules
  unsigned short* Vl = smem + 8192;  // [64 dims][128 keys], swizzled granules

  const float c2 = (float)invt_p[0] * 1.4426950408889634f;
  const int h = blockIdx.y;
  const int q0 = blockIdx.x * 64;
  const int tid = threadIdx.x;
  const int wave = tid >> 6;
  const int lane = tid & 63;
  const int qsub = wave >> 1;
  const int ksub = wave & 1;
  const int l31 = lane & 31;
  const int hi = lane >> 5;
  const int kz0 = blockIdx.z * (B2 / KSPLIT);

  // Q as B-operand frags: col = q (l31), k = m*16 + hi*8 + j
  short8 qf[4];
  {
    const int qrow = q0 + qsub * 32 + l31;
#pragma unroll
    for (int m = 0; m < 4; ++m)
      qf[m] = *(const short8*)&qb[(size_t)qrow * DMODEL + h * DH + m * 16 + hi * 8];
  }

  floatx16 oacc[2];
#pragma unroll
  for (int dt = 0; dt < 2; ++dt)
#pragma unroll
    for (int r = 0; r < 16; ++r) oacc[dt][r] = 0.f;
  float lsum = 0.f;

  // register prefetch (pre-swizzled global source, linear LDS store)
  ushort8 kr[4], vr[4];
#pragma unroll
  for (int i = 0; i < 4; ++i) {
    const int s = i * 256 + tid;
    const int key = s >> 3, cpk = s & 7, chk = cpk ^ (key & 7);
    kr[i] = *(const ushort8*)&kb[(size_t)(kz0 + key) * DMODEL + h * DH + chk * 8];
    const int d = s >> 4, cpv = s & 15, chv = cpv ^ (d & 15);
    vr[i] = *(const ushort8*)&vt[(size_t)(h * DH + d) * B2 + kz0 + chv * 8];
  }

  for (int c = 0; c < NCH; ++c) {
    __syncthreads();
#pragma unroll
    for (int i = 0; i < 4; ++i) {
      const int s = i * 256 + tid;
      const int key = s >> 3, cpk = s & 7;
      *(ushort8*)&Kl[key * 64 + cpk * 8] = kr[i];
      const int d = s >> 4, cpv = s & 15;
      *(ushort8*)&Vl[d * 128 + cpv * 8] = vr[i];
    }
    if (c + 1 < NCH) {
      const int kc0n = kz0 + (c + 1) * KC;
#pragma unroll
      for (int i = 0; i < 4; ++i) {
        const int s = i * 256 + tid;
        const int key = s >> 3, cpk = s & 7, chk = cpk ^ (key & 7);
        kr[i] = *(const ushort8*)&kb[(size_t)(kc0n + key) * DMODEL + h * DH + chk * 8];
        const int d = s >> 4, cpv = s & 15, chv = cpv ^ (d & 15);
        vr[i] = *(const ushort8*)&vt[(size_t)(h * DH + d) * B2 + kc0n + chv * 8];
      }
    }
    __syncthreads();

#pragma unroll
    for (int kt = 0; kt < 2; ++kt) {
      // ---- QK^T: S[key 32][q 32], A = K (row=key, k=dim), B = Q ----
      floatx16 s;
#pragma unroll
      for (int r = 0; r < 16; ++r) s[r] = 0.f;
      const int keyrow = ksub * 64 + kt * 32 + l31;
#pragma unroll
      for (int m = 0; m < 4; ++m) {
        const int g = (2 * m + hi) ^ (keyrow & 7);
        const short8 kf = *(const short8*)&Kl[keyrow * 64 + g * 8];
        s = __builtin_amdgcn_mfma_f32_32x32x16_bf16(kf, qf[m], s, 0, 0, 0);
      }
      // ---- softmax (cosine scores <= 1, so exp2(c2*(s-1)) needs no max) ----
      // s[r] holds S[key_local=(r&3)+8*(r>>2)+4*hi][q=l31] for this tile.
      // pk[i] = keys (pairs): i=0:(4hi,4hi+1) 1:(4hi+2,4hi+3) 2:(8+4hi,..)
      //         3:(8+4hi+2,..) 4..7: same +16.
      unsigned pk[8];
#pragma unroll
      for (int i = 0; i < 8; ++i) {
        const float e0 = exp2f(fmaf(s[2 * i], c2, -c2));
        const float e1 = exp2f(fmaf(s[2 * i + 1], c2, -c2));
        lsum += e0 + e1;
        pk[i] = (unsigned)f2bf(e0) | ((unsigned)f2bf(e1) << 16);
      }
      // NATURAL A-frags: k-slot (hi,j) <-> key 16p + (j<4 ? 4hi+j : 8+4hi+j-4)
      const uintx4 w0 = {pk[0], pk[1], pk[2], pk[3]};
      const uintx4 w1 = {pk[4], pk[5], pk[6], pk[7]};
      const short8 pa0 = __builtin_bit_cast(short8, w0);
      const short8 pa1 = __builtin_bit_cast(short8, w1);
      // ---- PV: oacc[dt] += P * V; B-frag slot j = V[key(hi,j)][d] ----
      // vf for mfma p: lo 4 = half hi of granule G=base+2p, hi 4 = of G+1.
      const int gb = ksub * 8 + kt * 4;
#pragma unroll
      for (int dt = 0; dt < 2; ++dt) {
        const int d = dt * 32 + l31;
        const int swz = l31 & 15;
        const unsigned short* Vr = &Vl[d * 128];
        const ushort4v a0 = *(const ushort4v*)&Vr[((gb + 0) ^ swz) * 8 + hi * 4];
        const ushort4v b0 = *(const ushort4v*)&Vr[((gb + 1) ^ swz) * 8 + hi * 4];
        const ushort4v a1 = *(const ushort4v*)&Vr[((gb + 2) ^ swz) * 8 + hi * 4];
        const ushort4v b1 = *(const ushort4v*)&Vr[((gb + 3) ^ swz) * 8 + hi * 4];
        const ushort8 t0 = {a0[0], a0[1], a0[2], a0[3], b0[0], b0[1], b0[2], b0[3]};
        const ushort8 t1 = {a1[0], a1[1], a1[2], a1[3], b1[0], b1[1], b1[2], b1[3]};
        const short8 vf0 = __builtin_bit_cast(short8, t0);
        const short8 vf1 = __builtin_bit_cast(short8, t1);
        oacc[dt] = __builtin_amdgcn_mfma_f32_32x32x16_bf16(pa0, vf0, oacc[dt], 0, 0, 0);
        oacc[dt] = __builtin_amdgcn_mfma_f32_32x32x16_bf16(pa1, vf1, oacc[dt], 0, 0, 0);
      }
    }
  }

  // lsum: lane and lane^32 hold the two key-halves of the same q
  lsum += __shfl_xor(lsum, 32, 64);
  if (hi == 0)
    atomicAdd(&lacc[(q0 + qsub * 32 + l31) * NH + h], lsum);

  // combine ksub halves via LDS, then atomicAdd into global accumulator
  __syncthreads();
  float* Osc = (float*)smem;  // [64 q][64 d] f32 = 16 KiB
  if (ksub == 1) {
#pragma unroll
    for (int dt = 0; dt < 2; ++dt)
#pragma unroll
      for (int r = 0; r < 16; ++r) {
        const int row = qsub * 32 + (r & 3) + 8 * (r >> 2) + 4 * hi;
        Osc[row * 64 + dt * 32 + l31] = oacc[dt][r];
      }
  }
  __syncthreads();
  if (ksub == 0) {
#pragma unroll
    for (int dt = 0; dt < 2; ++dt)
#pragma unroll
      for (int r = 0; r < 16; ++r) {
        const int row = qsub * 32 + (r & 3) + 8 * (r >> 2) + 4 * hi;
        const float v = oacc[dt][r] + Osc[row * 64 + dt * 32 + l31];
        atomicAdd(&aoacc[(size_t)(q0 + row) * DMODEL + h * DH + dt * 32 + l31], v);
      }
  }
}

// ---------------------------------------------------------------------------
// Wo projection with FUSED ao-normalize in A-staging:
// A[row][col] = bf16( aoacc[row][col] / lacc[row][col>>6] ), B = Woh (gload16).
// C = f32 woout [B1, 768]. 96 blocks.
// ---------------------------------------------------------------------------
__global__ __launch_bounds__(256) void wo_proj(
    const float* __restrict__ aoacc, const float* __restrict__ lacc,
    const unsigned short* __restrict__ Woh, float* __restrict__ woout) {
  __shared__ __align__(16) unsigned short sAh[4096], sBh[4096];
  const int bi = blockIdx.x;
  const int m0 = (bi / 6) * 128;
  const int n0 = (bi % 6) * 128;
  const int tid = threadIdx.x;
  const int wave = tid >> 6;
  const int lane = tid & 63;
  const int wm = wave >> 1;
  const int wn = wave & 1;
  const int n15 = lane & 15;
  const int quad = lane >> 4;
  const int srow = lane >> 2;
  const int cpl = (lane & 3) ^ (srow >> 2);

  floatx4 acc[4][4];
#pragma unroll
  for (int i = 0; i < 4; ++i)
#pragma unroll
    for (int j = 0; j < 4; ++j) acc[i][j] = (floatx4){0.f, 0.f, 0.f, 0.f};

  for (int k0 = 0; k0 < DMODEL; k0 += 32) {
    __syncthreads();
#pragma unroll
    for (int jj = 0; jj < 2; ++jj) {
      const int j = wave * 2 + jj;
      const int row = j * 16 + srow;
      // A: load 8 f32 from aoacc, normalize, convert, ds_write 16B
      const size_t ga = (size_t)(m0 + row) * DMODEL + k0 + cpl * 8;
      const float4 a0 = *(const float4*)&aoacc[ga];
      const float4 a1 = *(const float4*)&aoacc[ga + 4];
      const int head = (k0 + cpl * 8) >> 6;
      const float inv = 1.0f / lacc[(m0 + row) * NH + head];
      ushort8 ah = {f2bf(a0.x * inv), f2bf(a0.y * inv), f2bf(a0.z * inv),
                    f2bf(a0.w * inv), f2bf(a1.x * inv), f2bf(a1.y * inv),
                    f2bf(a1.z * inv), f2bf(a1.w * inv)};
      *(ushort8*)&sAh[j * 512 + lane * 8] = ah;
      // B: async staging
      gload16(Woh + (size_t)(n0 + row) * DMODEL + k0 + cpl * 8, &sBh[j * 512]);
    }
    __syncthreads();

    short8 afh[4];
#pragma unroll
    for (int mt = 0; mt < 4; ++mt) {
      const int row = wm * 64 + mt * 16 + n15;
      afh[mt] = *(const short8*)&sAh[row * 32 + ((quad ^ (n15 >> 2)) << 3)];
    }
#pragma unroll
    for (int nt = 0; nt < 4; ++nt) {
      const int row = wn * 64 + nt * 16 + n15;
      const short8 bfh = *(const short8*)&sBh[row * 32 + ((quad ^ (n15 >> 2)) << 3)];
#pragma unroll
      for (int mt = 0; mt < 4; ++mt)
        acc[mt][nt] = __builtin_amdgcn_mfma_f32_16x16x32_bf16(afh[mt], bfh, acc[mt][nt], 0, 0, 0);
    }
  }

#pragma unroll
  for (int mt = 0; mt < 4; ++mt)
#pragma unroll
    for (int nt = 0; nt < 4; ++nt)
#pragma unroll
      for (int rr = 0; rr < 4; ++rr) {
        const int row = m0 + wm * 64 + mt * 16 + quad * 4 + rr;
        const int col = n0 + wn * 64 + nt * 16 + n15;
        woout[(size_t)row * DMODEL + col] = acc[mt][nt][rr];
      }
}

// ---------------------------------------------------------------------------
__global__ __launch_bounds__(256) void l2norm_rows768_out(
    const float* __restrict__ x, float* __restrict__ out) {
  const int row = blockIdx.x;
  const float* xr = &x[(size_t)row * DMODEL];
  float ss = 0.0f;
  float vals[3];
#pragma unroll
  for (int i = 0; i < 3; ++i) {
    vals[i] = xr[threadIdx.x + i * 256];
    ss += vals[i] * vals[i];
  }
#pragma unroll
  for (int off = 32; off > 0; off >>= 1) ss += __shfl_xor(ss, off, 64);
  __shared__ float ws[4];
  if ((threadIdx.x & 63) == 0) ws[threadIdx.x >> 6] = ss;
  __syncthreads();
  const float tot = ws[0] + ws[1] + ws[2] + ws[3];
  const float sc = 1.0f / fmaxf(sqrtf(tot), 1e-12f);
  float* orow = &out[(size_t)row * DMODEL];
#pragma unroll
  for (int i = 0; i < 3; ++i) orow[threadIdx.x + i * 256] = vals[i] * sc;
}

// ---------------------------------------------------------------------------
extern "C" void kernel_launch(void* const* d_in, const int* in_sizes, int n_in,
                              void* d_out, int out_size, void* d_ws,
                              size_t ws_size, hipStream_t stream) {
  const float* x1 = (const float*)d_in[0];
  const float* x2 = (const float*)d_in[1];
  const float* Wq = (const float*)d_in[2];
  const float* Wk = (const float*)d_in[3];
  const float* Wv = (const float*)d_in[4];
  const float* Wo = (const float*)d_in[5];
  const int* invt = (const int*)d_in[6];
  float* outp = (float*)d_out;

  // workspace (bytes). Aliases are lifetime-safe under stream serialization:
  //  aoacc  <- x1h/x1l region (x1* dead after qk_proj; zeroed in v_zero)
  //  vt_bf  <- x2l region (x2l dead after qk_proj)
  //  woout  <- inside x2h region (x2h dead after v_zero)
  //  lacc   <- own region after k_bf (zeroed in v_zero)
  char* ws = (char*)d_ws;
  unsigned short* x1h = (unsigned short*)(ws + 0);
  unsigned short* x1l = (unsigned short*)(ws + 3145728);
  unsigned short* x2h = (unsigned short*)(ws + 6291456);
  unsigned short* x2l = (unsigned short*)(ws + 18874368);
  unsigned short* Wqh = (unsigned short*)(ws + 31457280);
  unsigned short* Wql = (unsigned short*)(ws + 32636928);
  unsigned short* Wkh = (unsigned short*)(ws + 33816576);
  unsigned short* Wkl = (unsigned short*)(ws + 34996224);
  unsigned short* Wvh = (unsigned short*)(ws + 36175872);
  unsigned short* Woh = (unsigned short*)(ws + 37355520);
  unsigned short* q_bf = (unsigned short*)(ws + 38535168);
  unsigned short* k_bf = (unsigned short*)(ws + 41680896);
  float* lacc = (float*)(ws + 54263808);                     // end 54362112
  // aliases:
  float* aoacc = (float*)(ws + 0);
  unsigned short* vt_bf = (unsigned short*)(ws + 18874368);
  float* woout = (float*)(ws + 9437184);

  // 1) all prep in one launch
  prep_all<<<9984, 256, 0, stream>>>(x1, x1h, x1l, x2, x2h, x2l, Wq, Wqh, Wql,
                                     Wk, Wkh, Wkl, Wv, Wvh, Wo, Woh);
  // 2) q-proj + k-proj fused (split precision + per-head l2norm)
  qk_proj<<<480, 256, 0, stream>>>(x1h, x1l, Wqh, Wql, x2h, x2l, Wkh, Wkl,
                                   q_bf, k_bf);
  // 3) v-proj + zero accumulators fused
  v_zero<<<774, 256, 0, stream>>>(Wvh, x2h, vt_bf, aoacc, lacc);
  // 4) attention (32x32, natural-order PV, KSPLIT=2)
  attn_mfma<<<dim3(B1 / 64, NH, KSPLIT), 256, 0, stream>>>(q_bf, k_bf, vt_bf,
                                                           aoacc, lacc, invt);
  // 5) Wo projection with fused ao-normalize staging
  wo_proj<<<96, 256, 0, stream>>>(aoacc, lacc, Woh, woout);
  // 6) final row l2norm
  l2norm_rows768_out<<<B1, 256, 0, stream>>>(woout, outp);
}

// Round 5
// 373.799 us; speedup vs baseline: 1.3500x; 1.3500x over previous
//
#include <hip/hip_runtime.h>
#include <hip/hip_bf16.h>
#include <math.h>

#define B1 2048
#define B2 8192
#define NH 12
#define DH 64
#define DMODEL 768

typedef __attribute__((ext_vector_type(8))) short short8;
typedef __attribute__((ext_vector_type(4))) float floatx4;
typedef __attribute__((ext_vector_type(8))) unsigned short ushort8;
typedef __attribute__((ext_vector_type(4))) unsigned short ushort4v;

static __device__ __forceinline__ unsigned short f2bf(float f) {
  __bf16 b = (__bf16)f;
  return __builtin_bit_cast(unsigned short, b);
}
static __device__ __forceinline__ float bf2f(unsigned short u) {
  return __builtin_bit_cast(float, ((unsigned)u) << 16);
}

// async global->LDS, 16B per lane; LDS dest = wave-uniform base + lane*16
static __device__ __forceinline__ void gload16(const unsigned short* g,
                                               unsigned short* l) {
  __builtin_amdgcn_global_load_lds(
      (const __attribute__((address_space(1))) void*)g,
      (__attribute__((address_space(3))) void*)l, 16, 0, 0);
}

// ---------------------------------------------------------------------------
// Fused prep: ALL fp32 -> bf16 hi/lo splits + hi-only converts, one launch.
// block-role table: [0,1536) x1 | [1536,7680) x2 | [7680,8256) Wq |
// [8256,8832) Wk | [8832,9408) Wv(hi only) | [9408,9984) Wo(hi only)
// ---------------------------------------------------------------------------
__global__ __launch_bounds__(256) void prep_all(
    const float* __restrict__ x1, unsigned short* __restrict__ x1h,
    unsigned short* __restrict__ x1l, const float* __restrict__ x2,
    unsigned short* __restrict__ x2h, unsigned short* __restrict__ x2l,
    const float* __restrict__ Wq, unsigned short* __restrict__ Wqh,
    unsigned short* __restrict__ Wql, const float* __restrict__ Wk,
    unsigned short* __restrict__ Wkh, unsigned short* __restrict__ Wkl,
    const float* __restrict__ Wv, unsigned short* __restrict__ Wvh,
    const float* __restrict__ Wo, unsigned short* __restrict__ Woh) {
  const int bi = blockIdx.x;
  const float* src;
  unsigned short *hi, *lo = nullptr;
  int lb;
  if (bi < 1536) {
    src = x1; hi = x1h; lo = x1l; lb = bi;
  } else if (bi < 7680) {
    src = x2; hi = x2h; lo = x2l; lb = bi - 1536;
  } else if (bi < 8256) {
    src = Wq; hi = Wqh; lo = Wql; lb = bi - 7680;
  } else if (bi < 8832) {
    src = Wk; hi = Wkh; lo = Wkl; lb = bi - 8256;
  } else if (bi < 9408) {
    src = Wv; hi = Wvh; lb = bi - 8832;
  } else {
    src = Wo; hi = Woh; lb = bi - 9408;
  }
  const int i = (lb * 256 + threadIdx.x) * 4;
  const float4 v = *(const float4*)&src[i];
  ushort4v h = {f2bf(v.x), f2bf(v.y), f2bf(v.z), f2bf(v.w)};
  *(ushort4v*)&hi[i] = h;
  if (lo) {
    ushort4v l = {f2bf(v.x - bf2f(h[0])), f2bf(v.y - bf2f(h[1])),
                  f2bf(v.z - bf2f(h[2])), f2bf(v.w - bf2f(h[3]))};
    *(ushort4v*)&lo[i] = l;
  }
}

// ---------------------------------------------------------------------------
// Core bf16 MFMA GEMM tile: C[M,N] = A[M,K]*B[N,K]^T (both K-contiguous).
// 128x128 tile, BK=32, 4 waves (2x2), 64x64/wave, global_load_lds staging,
// XOR-swizzled granules. SPLIT: hi/lo 3-MFMA k-step (~fp32). L2N: per-64-col
// L2 norm epilogue.
// ---------------------------------------------------------------------------
template <bool SPLIT, bool L2N, bool F32OUT>
static __device__ __forceinline__ void gemm_tile(
    const unsigned short* __restrict__ Ahg, const unsigned short* __restrict__ Alg,
    const unsigned short* __restrict__ Bhg, const unsigned short* __restrict__ Blg,
    void* __restrict__ Cv, int M, int N, int K, int m0, int n0,
    unsigned short* sAh, unsigned short* sBh, unsigned short* sAl,
    unsigned short* sBl) {
  const int tid = threadIdx.x;
  const int wave = tid >> 6;
  const int lane = tid & 63;
  const int wm = wave >> 1;
  const int wn = wave & 1;
  const int n15 = lane & 15;
  const int quad = lane >> 4;
  const int srow = lane >> 2;
  const int cpl = (lane & 3) ^ (srow >> 2);

  floatx4 acc[4][4];
#pragma unroll
  for (int i = 0; i < 4; ++i)
#pragma unroll
    for (int j = 0; j < 4; ++j) acc[i][j] = (floatx4){0.f, 0.f, 0.f, 0.f};

  for (int k0 = 0; k0 < K; k0 += 32) {
    __syncthreads();
#pragma unroll
    for (int jj = 0; jj < 2; ++jj) {
      const int j = wave * 2 + jj;
      const int row = j * 16 + srow;
      const size_t goffA = (size_t)(m0 + row) * K + k0 + cpl * 8;
      const size_t goffB = (size_t)(n0 + row) * K + k0 + cpl * 8;
      gload16(Ahg + goffA, &sAh[j * 512]);
      gload16(Bhg + goffB, &sBh[j * 512]);
      if constexpr (SPLIT) {
        gload16(Alg + goffA, &sAl[j * 512]);
        gload16(Blg + goffB, &sBl[j * 512]);
      }
    }
    __syncthreads();

    short8 afh[4], afl[4];
#pragma unroll
    for (int mt = 0; mt < 4; ++mt) {
      const int row = wm * 64 + mt * 16 + n15;
      const int off = row * 32 + ((quad ^ (n15 >> 2)) << 3);
      afh[mt] = *(const short8*)&sAh[off];
      if constexpr (SPLIT) afl[mt] = *(const short8*)&sAl[off];
    }
#pragma unroll
    for (int nt = 0; nt < 4; ++nt) {
      const int row = wn * 64 + nt * 16 + n15;
      const int off = row * 32 + ((quad ^ (n15 >> 2)) << 3);
      const short8 bfh = *(const short8*)&sBh[off];
      if constexpr (SPLIT) {
        const short8 bfl = *(const short8*)&sBl[off];
#pragma unroll
        for (int mt = 0; mt < 4; ++mt) {
          acc[mt][nt] = __builtin_amdgcn_mfma_f32_16x16x32_bf16(afh[mt], bfh, acc[mt][nt], 0, 0, 0);
          acc[mt][nt] = __builtin_amdgcn_mfma_f32_16x16x32_bf16(afh[mt], bfl, acc[mt][nt], 0, 0, 0);
          acc[mt][nt] = __builtin_amdgcn_mfma_f32_16x16x32_bf16(afl[mt], bfh, acc[mt][nt], 0, 0, 0);
        }
      } else {
#pragma unroll
        for (int mt = 0; mt < 4; ++mt)
          acc[mt][nt] = __builtin_amdgcn_mfma_f32_16x16x32_bf16(afh[mt], bfh, acc[mt][nt], 0, 0, 0);
      }
    }
  }

#pragma unroll
  for (int mt = 0; mt < 4; ++mt) {
    float scalev[4] = {1.f, 1.f, 1.f, 1.f};
    if constexpr (L2N) {
#pragma unroll
      for (int rr = 0; rr < 4; ++rr) {
        float ss = 0.f;
#pragma unroll
        for (int nt = 0; nt < 4; ++nt) ss += acc[mt][nt][rr] * acc[mt][nt][rr];
        ss += __shfl_xor(ss, 1, 64);
        ss += __shfl_xor(ss, 2, 64);
        ss += __shfl_xor(ss, 4, 64);
        ss += __shfl_xor(ss, 8, 64);
        scalev[rr] = 1.0f / fmaxf(sqrtf(ss), 1e-12f);
      }
    }
#pragma unroll
    for (int nt = 0; nt < 4; ++nt) {
#pragma unroll
      for (int rr = 0; rr < 4; ++rr) {
        const int row = m0 + wm * 64 + mt * 16 + quad * 4 + rr;
        const int col = n0 + wn * 64 + nt * 16 + n15;
        const float v = acc[mt][nt][rr] * scalev[rr];
        if constexpr (F32OUT)
          ((float*)Cv)[(size_t)row * N + col] = v;
        else
          ((unsigned short*)Cv)[(size_t)row * N + col] = f2bf(v);
      }
    }
  }
}

// ---------------------------------------------------------------------------
// Fused q-proj + k-proj (both SPLIT + per-head L2N, bf16 out). 480 blocks.
// ---------------------------------------------------------------------------
__global__ __launch_bounds__(256) void qk_proj(
    const unsigned short* __restrict__ x1h, const unsigned short* __restrict__ x1l,
    const unsigned short* __restrict__ Wqh, const unsigned short* __restrict__ Wql,
    const unsigned short* __restrict__ x2h, const unsigned short* __restrict__ x2l,
    const unsigned short* __restrict__ Wkh, const unsigned short* __restrict__ Wkl,
    unsigned short* __restrict__ qbf, unsigned short* __restrict__ kbf) {
  __shared__ __align__(16) unsigned short sAh[4096], sBh[4096], sAl[4096], sBl[4096];
  const int bi = blockIdx.x;
  if (bi < 96) {
    gemm_tile<true, true, false>(x1h, x1l, Wqh, Wql, qbf, B1, DMODEL, DMODEL,
                                 (bi / 6) * 128, (bi % 6) * 128, sAh, sBh, sAl, sBl);
  } else {
    const int b = bi - 96;
    gemm_tile<true, true, false>(x2h, x2l, Wkh, Wkl, kbf, B2, DMODEL, DMODEL,
                                 (b / 6) * 128, (b % 6) * 128, sAh, sBh, sAl, sBl);
  }
}

// ---------------------------------------------------------------------------
// v-proj only (vt = Wv @ x2^T, plain bf16). 384 blocks.
// (aoacc/lacc zeroing no longer needed: attention does plain slab stores.)
// ---------------------------------------------------------------------------
__global__ __launch_bounds__(256) void v_proj(
    const unsigned short* __restrict__ Wvh, const unsigned short* __restrict__ x2h,
    unsigned short* __restrict__ vtbf) {
  __shared__ __align__(16) unsigned short sAh[4096], sBh[4096];
  const int bi = blockIdx.x;
  gemm_tile<false, false, false>(Wvh, nullptr, x2h, nullptr, vtbf, DMODEL, B2,
                                 DMODEL, (bi / 64) * 128, (bi % 64) * 128,
                                 sAh, sBh, nullptr, nullptr);
}

// ---------------------------------------------------------------------------
// MFMA bf16 attention — R0 16x16 math, L2-DIRECT K/V (no staging, no
// main-loop barriers):
//  - K/V per (h, z-half) is 1 MB, shared by 32 blocks -> L2-resident.
//    Staging swizzle ∘ read swizzle = identity, so direct-read granules are
//    natural: K granule ks*4+quad, V granule ksub*8+ks*4+quad.
//  - P round-trip through wave-private LDS (Ps) exactly as R0 (verified).
//  - LDS = Ps only: 17408 B (was 50176).
//  - aoacc/lacc: per-z-slab PLAIN stores (each element owned by one block);
//    no atomics, no zeroing. wo_proj sums the slabs.
// ---------------------------------------------------------------------------
#define KC 128
#define KSPLIT 2
#define NCH (B2 / KSPLIT / KC)  // 32
#define PSTR 68

__global__ __launch_bounds__(256, 3) void attn_mfma(
    const unsigned short* __restrict__ qb, const unsigned short* __restrict__ kb,
    const unsigned short* __restrict__ vt, float* __restrict__ aoacc,
    float* __restrict__ lacc, const int* __restrict__ invt_p) {
  __shared__ __align__(16) unsigned short smem[8704];  // 17408 B: Ps / Osc+lsc

  const float c2 = (float)invt_p[0] * 1.4426950408889634f;
  const int h = blockIdx.y;
  const int q0 = blockIdx.x * 64;
  const int tid = threadIdx.x;
  const int wave = tid >> 6;
  const int lane = tid & 63;
  const int qsub = wave >> 1;
  const int ksub = wave & 1;
  const int n15 = lane & 15;
  const int quad = lane >> 4;
  const int kz0 = blockIdx.z * (B2 / KSPLIT);

  unsigned short* Ps = &smem[wave * 32 * PSTR];

  short8 qf[2][2];
#pragma unroll
  for (int qt = 0; qt < 2; ++qt)
#pragma unroll
    for (int ks = 0; ks < 2; ++ks) {
      const int qrow = q0 + qsub * 32 + qt * 16 + n15;
      qf[qt][ks] = *(const short8*)&qb[(size_t)qrow * DMODEL + h * DH + ks * 32 + quad * 8];
    }

  floatx4 oacc[2][4];
#pragma unroll
  for (int qt = 0; qt < 2; ++qt)
#pragma unroll
    for (int nt = 0; nt < 4; ++nt) oacc[qt][nt] = (floatx4){0.f, 0.f, 0.f, 0.f};
  float lsum[2] = {0.f, 0.f};

  const unsigned short* kbp = kb + (size_t)kz0 * DMODEL + h * DH;
  const unsigned short* vbp = vt + (size_t)(h * DH) * B2 + kz0;

  for (int c = 0; c < NCH; ++c) {
    const unsigned short* kc_ = kbp + (size_t)c * KC * DMODEL;
    const unsigned short* vc_ = vbp + c * KC;

#pragma unroll
    for (int kt = 0; kt < 4; ++kt) {
      floatx4 s0 = {0.f, 0.f, 0.f, 0.f}, s1 = {0.f, 0.f, 0.f, 0.f};
#pragma unroll
      for (int ks = 0; ks < 2; ++ks) {
        const short8 kf = *(const short8*)&kc_[
            (size_t)(ksub * 64 + kt * 16 + n15) * DMODEL + (ks * 4 + quad) * 8];
        s0 = __builtin_amdgcn_mfma_f32_16x16x32_bf16(kf, qf[0][ks], s0, 0, 0, 0);
        s1 = __builtin_amdgcn_mfma_f32_16x16x32_bf16(kf, qf[1][ks], s1, 0, 0, 0);
      }
      ushort4v p0, p1;
#pragma unroll
      for (int r = 0; r < 4; ++r) {
        const float e0 = exp2f(fmaf(s0[r], c2, -c2));
        const float e1 = exp2f(fmaf(s1[r], c2, -c2));
        lsum[0] += e0;
        lsum[1] += e1;
        p0[r] = f2bf(e0);
        p1[r] = f2bf(e1);
      }
      *(ushort4v*)&Ps[(0 * 16 + n15) * PSTR + kt * 16 + quad * 4] = p0;
      *(ushort4v*)&Ps[(1 * 16 + n15) * PSTR + kt * 16 + quad * 4] = p1;
    }

#pragma unroll
    for (int ks = 0; ks < 2; ++ks) {
      short8 pa[2];
#pragma unroll
      for (int qt = 0; qt < 2; ++qt)
        pa[qt] = *(const short8*)&Ps[(qt * 16 + n15) * PSTR + ks * 32 + quad * 8];
#pragma unroll
      for (int nt = 0; nt < 4; ++nt) {
        const short8 vf = *(const short8*)&vc_[
            (size_t)(nt * 16 + n15) * B2 + (ksub * 8 + ks * 4 + quad) * 8];
        oacc[0][nt] = __builtin_amdgcn_mfma_f32_16x16x32_bf16(pa[0], vf, oacc[0][nt], 0, 0, 0);
        oacc[1][nt] = __builtin_amdgcn_mfma_f32_16x16x32_bf16(pa[1], vf, oacc[1][nt], 0, 0, 0);
      }
    }
  }

#pragma unroll
  for (int qt = 0; qt < 2; ++qt) {
    float v = lsum[qt];
    v += __shfl_xor(v, 16, 64);
    v += __shfl_xor(v, 32, 64);
    lsum[qt] = v;
  }

  float* aoz = aoacc + (size_t)blockIdx.z * B1 * DMODEL;
  float* lz = lacc + (size_t)blockIdx.z * B1 * NH;

  __syncthreads();
  float* Osc = (float*)smem;        // [64 q][64 d] f32 = 16384 B
  float* lsc = Osc + 4096;          // [64 q] f32 = 256 B (total 16640 <= 17408)
  if (ksub == 1) {
#pragma unroll
    for (int qt = 0; qt < 2; ++qt)
#pragma unroll
      for (int nt = 0; nt < 4; ++nt)
#pragma unroll
        for (int r = 0; r < 4; ++r) {
          const int row = qsub * 32 + qt * 16 + quad * 4 + r;
          Osc[row * 64 + nt * 16 + n15] = oacc[qt][nt][r];
        }
    if (quad == 0) {
      lsc[qsub * 32 + n15] = lsum[0];
      lsc[qsub * 32 + 16 + n15] = lsum[1];
    }
  }
  __syncthreads();
  if (ksub == 0) {
#pragma unroll
    for (int qt = 0; qt < 2; ++qt)
#pragma unroll
      for (int nt = 0; nt < 4; ++nt)
#pragma unroll
        for (int r = 0; r < 4; ++r) {
          const int row = qsub * 32 + qt * 16 + quad * 4 + r;
          const float v = oacc[qt][nt][r] + Osc[row * 64 + nt * 16 + n15];
          aoz[(size_t)(q0 + row) * DMODEL + h * DH + nt * 16 + n15] = v;
        }
    if (quad == 0) {
      lz[(size_t)(q0 + qsub * 32 + n15) * NH + h] = lsum[0] + lsc[qsub * 32 + n15];
      lz[(size_t)(q0 + qsub * 32 + 16 + n15) * NH + h] =
          lsum[1] + lsc[qsub * 32 + 16 + n15];
    }
  }
}

// ---------------------------------------------------------------------------
// Wo projection with FUSED slab-sum + ao-normalize in A-staging:
// A[row][col] = bf16( (ao0+ao1)[row][col] / (l0+l1)[row][col>>6] ).
// B = Woh (gload16). C = f32 woout [B1, 768]. 96 blocks.
// ---------------------------------------------------------------------------
__global__ __launch_bounds__(256) void wo_proj(
    const float* __restrict__ aoacc, const float* __restrict__ lacc,
    const unsigned short* __restrict__ Woh, float* __restrict__ woout) {
  __shared__ __align__(16) unsigned short sAh[4096], sBh[4096];
  const int bi = blockIdx.x;
  const int m0 = (bi / 6) * 128;
  const int n0 = (bi % 6) * 128;
  const int tid = threadIdx.x;
  const int wave = tid >> 6;
  const int lane = tid & 63;
  const int wm = wave >> 1;
  const int wn = wave & 1;
  const int n15 = lane & 15;
  const int quad = lane >> 4;
  const int srow = lane >> 2;
  const int cpl = (lane & 3) ^ (srow >> 2);

  const float* ao1 = aoacc + (size_t)B1 * DMODEL;
  const float* la1 = lacc + (size_t)B1 * NH;

  floatx4 acc[4][4];
#pragma unroll
  for (int i = 0; i < 4; ++i)
#pragma unroll
    for (int j = 0; j < 4; ++j) acc[i][j] = (floatx4){0.f, 0.f, 0.f, 0.f};

  for (int k0 = 0; k0 < DMODEL; k0 += 32) {
    __syncthreads();
#pragma unroll
    for (int jj = 0; jj < 2; ++jj) {
      const int j = wave * 2 + jj;
      const int row = j * 16 + srow;
      // A: load 8 f32 from each slab, sum, normalize, convert, ds_write 16B
      const size_t ga = (size_t)(m0 + row) * DMODEL + k0 + cpl * 8;
      const float4 a0 = *(const float4*)&aoacc[ga];
      const float4 a1 = *(const float4*)&aoacc[ga + 4];
      const float4 b0 = *(const float4*)&ao1[ga];
      const float4 b1 = *(const float4*)&ao1[ga + 4];
      const int head = (k0 + cpl * 8) >> 6;
      const float lsum = lacc[(m0 + row) * NH + head] + la1[(m0 + row) * NH + head];
      const float inv = 1.0f / lsum;
      ushort8 ah = {f2bf((a0.x + b0.x) * inv), f2bf((a0.y + b0.y) * inv),
                    f2bf((a0.z + b0.z) * inv), f2bf((a0.w + b0.w) * inv),
                    f2bf((a1.x + b1.x) * inv), f2bf((a1.y + b1.y) * inv),
                    f2bf((a1.z + b1.z) * inv), f2bf((a1.w + b1.w) * inv)};
      *(ushort8*)&sAh[j * 512 + lane * 8] = ah;
      // B: async staging
      gload16(Woh + (size_t)(n0 + row) * DMODEL + k0 + cpl * 8, &sBh[j * 512]);
    }
    __syncthreads();

    short8 afh[4];
#pragma unroll
    for (int mt = 0; mt < 4; ++mt) {
      const int row = wm * 64 + mt * 16 + n15;
      afh[mt] = *(const short8*)&sAh[row * 32 + ((quad ^ (n15 >> 2)) << 3)];
    }
#pragma unroll
    for (int nt = 0; nt < 4; ++nt) {
      const int row = wn * 64 + nt * 16 + n15;
      const short8 bfh = *(const short8*)&sBh[row * 32 + ((quad ^ (n15 >> 2)) << 3)];
#pragma unroll
      for (int mt = 0; mt < 4; ++mt)
        acc[mt][nt] = __builtin_amdgcn_mfma_f32_16x16x32_bf16(afh[mt], bfh, acc[mt][nt], 0, 0, 0);
    }
  }

#pragma unroll
  for (int mt = 0; mt < 4; ++mt)
#pragma unroll
    for (int nt = 0; nt < 4; ++nt)
#pragma unroll
      for (int rr = 0; rr < 4; ++rr) {
        const int row = m0 + wm * 64 + mt * 16 + quad * 4 + rr;
        const int col = n0 + wn * 64 + nt * 16 + n15;
        woout[(size_t)row * DMODEL + col] = acc[mt][nt][rr];
      }
}

// ---------------------------------------------------------------------------
__global__ __launch_bounds__(256) void l2norm_rows768_out(
    const float* __restrict__ x, float* __restrict__ out) {
  const int row = blockIdx.x;
  const float* xr = &x[(size_t)row * DMODEL];
  float ss = 0.0f;
  float vals[3];
#pragma unroll
  for (int i = 0; i < 3; ++i) {
    vals[i] = xr[threadIdx.x + i * 256];
    ss += vals[i] * vals[i];
  }
#pragma unroll
  for (int off = 32; off > 0; off >>= 1) ss += __shfl_xor(ss, off, 64);
  __shared__ float ws[4];
  if ((threadIdx.x & 63) == 0) ws[threadIdx.x >> 6] = ss;
  __syncthreads();
  const float tot = ws[0] + ws[1] + ws[2] + ws[3];
  const float sc = 1.0f / fmaxf(sqrtf(tot), 1e-12f);
  float* orow = &out[(size_t)row * DMODEL];
#pragma unroll
  for (int i = 0; i < 3; ++i) orow[threadIdx.x + i * 256] = vals[i] * sc;
}

// ---------------------------------------------------------------------------
extern "C" void kernel_launch(void* const* d_in, const int* in_sizes, int n_in,
                              void* d_out, int out_size, void* d_ws,
                              size_t ws_size, hipStream_t stream) {
  const float* x1 = (const float*)d_in[0];
  const float* x2 = (const float*)d_in[1];
  const float* Wq = (const float*)d_in[2];
  const float* Wk = (const float*)d_in[3];
  const float* Wv = (const float*)d_in[4];
  const float* Wo = (const float*)d_in[5];
  const int* invt = (const int*)d_in[6];
  float* outp = (float*)d_out;

  // workspace (bytes). Aliases are lifetime-safe under stream serialization:
  //  aoacc slab0 <- x1h/x1l region (dead after qk_proj)     [0,        6291456)
  //  aoacc slab1 <- x2h first half (dead after v_proj)      [6291456, 12582912)
  //  woout       <- x2h second half (dead after v_proj)     [12582912,18874368)
  //  vt_bf       <- x2l region (dead after qk_proj)         [18874368,31457280)
  //  lacc slabs  <- Wql region (dead after qk_proj)         [32636928,32833536)
  char* ws = (char*)d_ws;
  unsigned short* x1h = (unsigned short*)(ws + 0);
  unsigned short* x1l = (unsigned short*)(ws + 3145728);
  unsigned short* x2h = (unsigned short*)(ws + 6291456);
  unsigned short* x2l = (unsigned short*)(ws + 18874368);
  unsigned short* Wqh = (unsigned short*)(ws + 31457280);
  unsigned short* Wql = (unsigned short*)(ws + 32636928);
  unsigned short* Wkh = (unsigned short*)(ws + 33816576);
  unsigned short* Wkl = (unsigned short*)(ws + 34996224);
  unsigned short* Wvh = (unsigned short*)(ws + 36175872);
  unsigned short* Woh = (unsigned short*)(ws + 37355520);
  unsigned short* q_bf = (unsigned short*)(ws + 38535168);
  unsigned short* k_bf = (unsigned short*)(ws + 41680896);   // end 54263808
  // aliases:
  float* aoacc = (float*)(ws + 0);                  // 2 slabs, 12582912 B
  float* lacc = (float*)(ws + 32636928);            // 2 slabs, 196608 B
  unsigned short* vt_bf = (unsigned short*)(ws + 18874368);
  float* woout = (float*)(ws + 12582912);

  // 1) all prep in one launch
  prep_all<<<9984, 256, 0, stream>>>(x1, x1h, x1l, x2, x2h, x2l, Wq, Wqh, Wql,
                                     Wk, Wkh, Wkl, Wv, Wvh, Wo, Woh);
  // 2) q-proj + k-proj fused (split precision + per-head l2norm)
  qk_proj<<<480, 256, 0, stream>>>(x1h, x1l, Wqh, Wql, x2h, x2l, Wkh, Wkl,
                                   q_bf, k_bf);
  // 3) v-proj
  v_proj<<<384, 256, 0, stream>>>(Wvh, x2h, vt_bf);
  // 4) attention (R0 math, L2-direct K/V, no main-loop barriers, slab stores)
  attn_mfma<<<dim3(B1 / 64, NH, KSPLIT), 256, 0, stream>>>(q_bf, k_bf, vt_bf,
                                                           aoacc, lacc, invt);
  // 5) Wo projection with fused slab-sum + ao-normalize staging
  wo_proj<<<96, 256, 0, stream>>>(aoacc, lacc, Woh, woout);
  // 6) final row l2norm
  l2norm_rows768_out<<<B1, 256, 0, stream>>>(woout, outp);
}

// Round 6
// 326.282 us; speedup vs baseline: 1.5466x; 1.1456x over previous
//
#include <hip/hip_runtime.h>
#include <hip/hip_bf16.h>
#include <math.h>

#define B1 2048
#define B2 8192
#define NH 12
#define DH 64
#define DMODEL 768

typedef __attribute__((ext_vector_type(8))) short short8;
typedef __attribute__((ext_vector_type(4))) float floatx4;
typedef __attribute__((ext_vector_type(8))) unsigned short ushort8;
typedef __attribute__((ext_vector_type(4))) unsigned short ushort4v;

static __device__ __forceinline__ unsigned short f2bf(float f) {
  __bf16 b = (__bf16)f;
  return __builtin_bit_cast(unsigned short, b);
}
static __device__ __forceinline__ float bf2f(unsigned short u) {
  return __builtin_bit_cast(float, ((unsigned)u) << 16);
}

// async global->LDS, 16B per lane; LDS dest = wave-uniform base + lane*16
static __device__ __forceinline__ void gload16(const unsigned short* g,
                                               unsigned short* l) {
  __builtin_amdgcn_global_load_lds(
      (const __attribute__((address_space(1))) void*)g,
      (__attribute__((address_space(3))) void*)l, 16, 0, 0);
}

// ---------------------------------------------------------------------------
// Fused prep: ALL fp32 -> bf16 hi/lo splits + hi-only converts, one launch.
// block-role table: [0,1536) x1 | [1536,7680) x2 | [7680,8256) Wq |
// [8256,8832) Wk | [8832,9408) Wv(hi only) | [9408,9984) Wo(hi only)
// ---------------------------------------------------------------------------
__global__ __launch_bounds__(256) void prep_all(
    const float* __restrict__ x1, unsigned short* __restrict__ x1h,
    unsigned short* __restrict__ x1l, const float* __restrict__ x2,
    unsigned short* __restrict__ x2h, unsigned short* __restrict__ x2l,
    const float* __restrict__ Wq, unsigned short* __restrict__ Wqh,
    unsigned short* __restrict__ Wql, const float* __restrict__ Wk,
    unsigned short* __restrict__ Wkh, unsigned short* __restrict__ Wkl,
    const float* __restrict__ Wv, unsigned short* __restrict__ Wvh,
    const float* __restrict__ Wo, unsigned short* __restrict__ Woh) {
  const int bi = blockIdx.x;
  const float* src;
  unsigned short *hi, *lo = nullptr;
  int lb;
  if (bi < 1536) {
    src = x1; hi = x1h; lo = x1l; lb = bi;
  } else if (bi < 7680) {
    src = x2; hi = x2h; lo = x2l; lb = bi - 1536;
  } else if (bi < 8256) {
    src = Wq; hi = Wqh; lo = Wql; lb = bi - 7680;
  } else if (bi < 8832) {
    src = Wk; hi = Wkh; lo = Wkl; lb = bi - 8256;
  } else if (bi < 9408) {
    src = Wv; hi = Wvh; lb = bi - 8832;
  } else {
    src = Wo; hi = Woh; lb = bi - 9408;
  }
  const int i = (lb * 256 + threadIdx.x) * 4;
  const float4 v = *(const float4*)&src[i];
  ushort4v h = {f2bf(v.x), f2bf(v.y), f2bf(v.z), f2bf(v.w)};
  *(ushort4v*)&hi[i] = h;
  if (lo) {
    ushort4v l = {f2bf(v.x - bf2f(h[0])), f2bf(v.y - bf2f(h[1])),
                  f2bf(v.z - bf2f(h[2])), f2bf(v.w - bf2f(h[3]))};
    *(ushort4v*)&lo[i] = l;
  }
}

// ---------------------------------------------------------------------------
// Core bf16 MFMA GEMM tile: C[M,N] = A[M,K]*B[N,K]^T (both K-contiguous).
// 128x128 tile, BK=32, 4 waves (2x2), 64x64/wave, global_load_lds staging,
// XOR-swizzled granules. SPLIT: hi/lo 3-MFMA k-step (~fp32). L2N: per-64-col
// L2 norm epilogue.
// ---------------------------------------------------------------------------
template <bool SPLIT, bool L2N, bool F32OUT>
static __device__ __forceinline__ void gemm_tile(
    const unsigned short* __restrict__ Ahg, const unsigned short* __restrict__ Alg,
    const unsigned short* __restrict__ Bhg, const unsigned short* __restrict__ Blg,
    void* __restrict__ Cv, int M, int N, int K, int m0, int n0,
    unsigned short* sAh, unsigned short* sBh, unsigned short* sAl,
    unsigned short* sBl) {
  const int tid = threadIdx.x;
  const int wave = tid >> 6;
  const int lane = tid & 63;
  const int wm = wave >> 1;
  const int wn = wave & 1;
  const int n15 = lane & 15;
  const int quad = lane >> 4;
  const int srow = lane >> 2;
  const int cpl = (lane & 3) ^ (srow >> 2);

  floatx4 acc[4][4];
#pragma unroll
  for (int i = 0; i < 4; ++i)
#pragma unroll
    for (int j = 0; j < 4; ++j) acc[i][j] = (floatx4){0.f, 0.f, 0.f, 0.f};

  for (int k0 = 0; k0 < K; k0 += 32) {
    __syncthreads();
#pragma unroll
    for (int jj = 0; jj < 2; ++jj) {
      const int j = wave * 2 + jj;
      const int row = j * 16 + srow;
      const size_t goffA = (size_t)(m0 + row) * K + k0 + cpl * 8;
      const size_t goffB = (size_t)(n0 + row) * K + k0 + cpl * 8;
      gload16(Ahg + goffA, &sAh[j * 512]);
      gload16(Bhg + goffB, &sBh[j * 512]);
      if constexpr (SPLIT) {
        gload16(Alg + goffA, &sAl[j * 512]);
        gload16(Blg + goffB, &sBl[j * 512]);
      }
    }
    __syncthreads();

    short8 afh[4], afl[4];
#pragma unroll
    for (int mt = 0; mt < 4; ++mt) {
      const int row = wm * 64 + mt * 16 + n15;
      const int off = row * 32 + ((quad ^ (n15 >> 2)) << 3);
      afh[mt] = *(const short8*)&sAh[off];
      if constexpr (SPLIT) afl[mt] = *(const short8*)&sAl[off];
    }
#pragma unroll
    for (int nt = 0; nt < 4; ++nt) {
      const int row = wn * 64 + nt * 16 + n15;
      const int off = row * 32 + ((quad ^ (n15 >> 2)) << 3);
      const short8 bfh = *(const short8*)&sBh[off];
      if constexpr (SPLIT) {
        const short8 bfl = *(const short8*)&sBl[off];
#pragma unroll
        for (int mt = 0; mt < 4; ++mt) {
          acc[mt][nt] = __builtin_amdgcn_mfma_f32_16x16x32_bf16(afh[mt], bfh, acc[mt][nt], 0, 0, 0);
          acc[mt][nt] = __builtin_amdgcn_mfma_f32_16x16x32_bf16(afh[mt], bfl, acc[mt][nt], 0, 0, 0);
          acc[mt][nt] = __builtin_amdgcn_mfma_f32_16x16x32_bf16(afl[mt], bfh, acc[mt][nt], 0, 0, 0);
        }
      } else {
#pragma unroll
        for (int mt = 0; mt < 4; ++mt)
          acc[mt][nt] = __builtin_amdgcn_mfma_f32_16x16x32_bf16(afh[mt], bfh, acc[mt][nt], 0, 0, 0);
      }
    }
  }

#pragma unroll
  for (int mt = 0; mt < 4; ++mt) {
    float scalev[4] = {1.f, 1.f, 1.f, 1.f};
    if constexpr (L2N) {
#pragma unroll
      for (int rr = 0; rr < 4; ++rr) {
        float ss = 0.f;
#pragma unroll
        for (int nt = 0; nt < 4; ++nt) ss += acc[mt][nt][rr] * acc[mt][nt][rr];
        ss += __shfl_xor(ss, 1, 64);
        ss += __shfl_xor(ss, 2, 64);
        ss += __shfl_xor(ss, 4, 64);
        ss += __shfl_xor(ss, 8, 64);
        scalev[rr] = 1.0f / fmaxf(sqrtf(ss), 1e-12f);
      }
    }
#pragma unroll
    for (int nt = 0; nt < 4; ++nt) {
#pragma unroll
      for (int rr = 0; rr < 4; ++rr) {
        const int row = m0 + wm * 64 + mt * 16 + quad * 4 + rr;
        const int col = n0 + wn * 64 + nt * 16 + n15;
        const float v = acc[mt][nt][rr] * scalev[rr];
        if constexpr (F32OUT)
          ((float*)Cv)[(size_t)row * N + col] = v;
        else
          ((unsigned short*)Cv)[(size_t)row * N + col] = f2bf(v);
      }
    }
  }
}

// ---------------------------------------------------------------------------
// Fused q-proj + k-proj (both SPLIT + per-head L2N, bf16 out). 480 blocks.
// ---------------------------------------------------------------------------
__global__ __launch_bounds__(256) void qk_proj(
    const unsigned short* __restrict__ x1h, const unsigned short* __restrict__ x1l,
    const unsigned short* __restrict__ Wqh, const unsigned short* __restrict__ Wql,
    const unsigned short* __restrict__ x2h, const unsigned short* __restrict__ x2l,
    const unsigned short* __restrict__ Wkh, const unsigned short* __restrict__ Wkl,
    unsigned short* __restrict__ qbf, unsigned short* __restrict__ kbf) {
  __shared__ __align__(16) unsigned short sAh[4096], sBh[4096], sAl[4096], sBl[4096];
  const int bi = blockIdx.x;
  if (bi < 96) {
    gemm_tile<true, true, false>(x1h, x1l, Wqh, Wql, qbf, B1, DMODEL, DMODEL,
                                 (bi / 6) * 128, (bi % 6) * 128, sAh, sBh, sAl, sBl);
  } else {
    const int b = bi - 96;
    gemm_tile<true, true, false>(x2h, x2l, Wkh, Wkl, kbf, B2, DMODEL, DMODEL,
                                 (b / 6) * 128, (b % 6) * 128, sAh, sBh, sAl, sBl);
  }
}

// ---------------------------------------------------------------------------
// v-proj only (vt = Wv @ x2^T, plain bf16). 384 blocks.
// (aoacc/lacc zeroing not needed: attention does plain slab stores.)
// ---------------------------------------------------------------------------
__global__ __launch_bounds__(256) void v_proj(
    const unsigned short* __restrict__ Wvh, const unsigned short* __restrict__ x2h,
    unsigned short* __restrict__ vtbf) {
  __shared__ __align__(16) unsigned short sAh[4096], sBh[4096];
  const int bi = blockIdx.x;
  gemm_tile<false, false, false>(Wvh, nullptr, x2h, nullptr, vtbf, DMODEL, B2,
                                 DMODEL, (bi / 64) * 128, (bi % 64) * 128,
                                 sAh, sBh, nullptr, nullptr);
}

// ---------------------------------------------------------------------------
// MFMA bf16 attention — R0 pipeline, V-direct, slab stores, XCD swizzle:
//  - K staged in LDS with register prefetch (R0-verified pipeline: issue
//    chunk c+1's K loads before computing chunk c).
//  - V read DIRECT from L2 in the PV phase (R5-verified indexing; m169:
//    V-staging is pure overhead when K/V L2-fit).
//  - P round-trip through wave-private LDS (Ps) exactly as R0.
//  - LDS = Kl(16K) + Ps(17408) = 33792 B.
//  - aoacc/lacc: per-z-slab PLAIN stores (no atomics, no zeroing).
//  - 1D grid 768 with XCD-aware swizzle: each (h,z) pair's 32 q-blocks on
//    one XCD -> K/V fetched ~once per XCD instead of ~8x.
// ---------------------------------------------------------------------------
#define KC 128
#define KSPLIT 2
#define NCH (B2 / KSPLIT / KC)  // 32
#define PSTR 68

__global__ __launch_bounds__(256, 3) void attn_mfma(
    const unsigned short* __restrict__ qb, const unsigned short* __restrict__ kb,
    const unsigned short* __restrict__ vt, float* __restrict__ aoacc,
    float* __restrict__ lacc, const int* __restrict__ invt_p) {
  __shared__ __align__(16) unsigned short smem[16896];  // 33792 B
  unsigned short* Kl = smem;            // [128 keys][64 dims], swizzled granules
  unsigned short* Psl = smem + 8192;    // 4 waves x 32 x PSTR

  // XCD swizzle: 96 consecutive swz per XCD = 3 full (h,z) pairs of 32 blocks
  const int bid = blockIdx.x;                     // 0..767
  const int swz = (bid & 7) * 96 + (bid >> 3);    // bijective (768 % 8 == 0)
  const int zz = swz / 384;
  const int rem = swz - zz * 384;
  const int h = rem >> 5;
  const int q0 = (rem & 31) * 64;

  const float c2 = (float)invt_p[0] * 1.4426950408889634f;
  const int tid = threadIdx.x;
  const int wave = tid >> 6;
  const int lane = tid & 63;
  const int qsub = wave >> 1;
  const int ksub = wave & 1;
  const int n15 = lane & 15;
  const int quad = lane >> 4;
  const int kz0 = zz * (B2 / KSPLIT);

  unsigned short* Ps = &Psl[wave * 32 * PSTR];

  short8 qf[2][2];
#pragma unroll
  for (int qt = 0; qt < 2; ++qt)
#pragma unroll
    for (int ks = 0; ks < 2; ++ks) {
      const int qrow = q0 + qsub * 32 + qt * 16 + n15;
      qf[qt][ks] = *(const short8*)&qb[(size_t)qrow * DMODEL + h * DH + ks * 32 + quad * 8];
    }

  floatx4 oacc[2][4];
#pragma unroll
  for (int qt = 0; qt < 2; ++qt)
#pragma unroll
    for (int nt = 0; nt < 4; ++nt) oacc[qt][nt] = (floatx4){0.f, 0.f, 0.f, 0.f};
  float lsum[2] = {0.f, 0.f};

  const unsigned short* kbp = kb + (size_t)kz0 * DMODEL + h * DH;
  const unsigned short* vbp = vt + (size_t)(h * DH) * B2 + kz0;

  // K register prefetch (pre-swizzled global source, linear LDS store)
  ushort8 kr[4];
#pragma unroll
  for (int i = 0; i < 4; ++i) {
    const int s = i * 256 + tid;
    const int key = s >> 3, cpk = s & 7, chk = cpk ^ (key & 7);
    kr[i] = *(const ushort8*)&kbp[(size_t)key * DMODEL + chk * 8];
  }

  for (int c = 0; c < NCH; ++c) {
    __syncthreads();
#pragma unroll
    for (int i = 0; i < 4; ++i) {
      const int s = i * 256 + tid;
      const int key = s >> 3, cpk = s & 7;
      *(ushort8*)&Kl[key * 64 + cpk * 8] = kr[i];
    }
    if (c + 1 < NCH) {
      const unsigned short* kn = kbp + (size_t)(c + 1) * KC * DMODEL;
#pragma unroll
      for (int i = 0; i < 4; ++i) {
        const int s = i * 256 + tid;
        const int key = s >> 3, cpk = s & 7, chk = cpk ^ (key & 7);
        kr[i] = *(const ushort8*)&kn[(size_t)key * DMODEL + chk * 8];
      }
    }
    __syncthreads();

#pragma unroll
    for (int kt = 0; kt < 4; ++kt) {
      floatx4 s0 = {0.f, 0.f, 0.f, 0.f}, s1 = {0.f, 0.f, 0.f, 0.f};
#pragma unroll
      for (int ks = 0; ks < 2; ++ks) {
        const int key = ksub * 64 + kt * 16 + n15;
        const int cp = (ks * 4 + quad) ^ (n15 & 7);
        const short8 kf = *(const short8*)&Kl[key * 64 + cp * 8];
        s0 = __builtin_amdgcn_mfma_f32_16x16x32_bf16(kf, qf[0][ks], s0, 0, 0, 0);
        s1 = __builtin_amdgcn_mfma_f32_16x16x32_bf16(kf, qf[1][ks], s1, 0, 0, 0);
      }
      ushort4v p0, p1;
#pragma unroll
      for (int r = 0; r < 4; ++r) {
        const float e0 = exp2f(fmaf(s0[r], c2, -c2));
        const float e1 = exp2f(fmaf(s1[r], c2, -c2));
        lsum[0] += e0;
        lsum[1] += e1;
        p0[r] = f2bf(e0);
        p1[r] = f2bf(e1);
      }
      *(ushort4v*)&Ps[(0 * 16 + n15) * PSTR + kt * 16 + quad * 4] = p0;
      *(ushort4v*)&Ps[(1 * 16 + n15) * PSTR + kt * 16 + quad * 4] = p1;
    }

    const unsigned short* vc_ = vbp + c * KC;
#pragma unroll
    for (int ks = 0; ks < 2; ++ks) {
      short8 pa[2];
#pragma unroll
      for (int qt = 0; qt < 2; ++qt)
        pa[qt] = *(const short8*)&Ps[(qt * 16 + n15) * PSTR + ks * 32 + quad * 8];
#pragma unroll
      for (int nt = 0; nt < 4; ++nt) {
        const short8 vf = *(const short8*)&vc_[
            (size_t)(nt * 16 + n15) * B2 + (ksub * 8 + ks * 4 + quad) * 8];
        oacc[0][nt] = __builtin_amdgcn_mfma_f32_16x16x32_bf16(pa[0], vf, oacc[0][nt], 0, 0, 0);
        oacc[1][nt] = __builtin_amdgcn_mfma_f32_16x16x32_bf16(pa[1], vf, oacc[1][nt], 0, 0, 0);
      }
    }
  }

#pragma unroll
  for (int qt = 0; qt < 2; ++qt) {
    float v = lsum[qt];
    v += __shfl_xor(v, 16, 64);
    v += __shfl_xor(v, 32, 64);
    lsum[qt] = v;
  }

  float* aoz = aoacc + (size_t)zz * B1 * DMODEL;
  float* lz = lacc + (size_t)zz * B1 * NH;

  __syncthreads();
  float* Osc = (float*)smem;        // [64 q][64 d] f32 = 16384 B
  float* lsc = Osc + 4096;          // [64 q] f32 (total 16640 <= 33792)
  if (ksub == 1) {
#pragma unroll
    for (int qt = 0; qt < 2; ++qt)
#pragma unroll
      for (int nt = 0; nt < 4; ++nt)
#pragma unroll
        for (int r = 0; r < 4; ++r) {
          const int row = qsub * 32 + qt * 16 + quad * 4 + r;
          Osc[row * 64 + nt * 16 + n15] = oacc[qt][nt][r];
        }
    if (quad == 0) {
      lsc[qsub * 32 + n15] = lsum[0];
      lsc[qsub * 32 + 16 + n15] = lsum[1];
    }
  }
  __syncthreads();
  if (ksub == 0) {
#pragma unroll
    for (int qt = 0; qt < 2; ++qt)
#pragma unroll
      for (int nt = 0; nt < 4; ++nt)
#pragma unroll
        for (int r = 0; r < 4; ++r) {
          const int row = qsub * 32 + qt * 16 + quad * 4 + r;
          const float v = oacc[qt][nt][r] + Osc[row * 64 + nt * 16 + n15];
          aoz[(size_t)(q0 + row) * DMODEL + h * DH + nt * 16 + n15] = v;
        }
    if (quad == 0) {
      lz[(size_t)(q0 + qsub * 32 + n15) * NH + h] = lsum[0] + lsc[qsub * 32 + n15];
      lz[(size_t)(q0 + qsub * 32 + 16 + n15) * NH + h] =
          lsum[1] + lsc[qsub * 32 + 16 + n15];
    }
  }
}

// ---------------------------------------------------------------------------
// Wo projection with FUSED slab-sum + ao-normalize in A-staging:
// A[row][col] = bf16( (ao0+ao1)[row][col] / (l0+l1)[row][col>>6] ).
// B = Woh (gload16). C = f32 woout [B1, 768]. 96 blocks.
// ---------------------------------------------------------------------------
__global__ __launch_bounds__(256) void wo_proj(
    const float* __restrict__ aoacc, const float* __restrict__ lacc,
    const unsigned short* __restrict__ Woh, float* __restrict__ woout) {
  __shared__ __align__(16) unsigned short sAh[4096], sBh[4096];
  const int bi = blockIdx.x;
  const int m0 = (bi / 6) * 128;
  const int n0 = (bi % 6) * 128;
  const int tid = threadIdx.x;
  const int wave = tid >> 6;
  const int lane = tid & 63;
  const int wm = wave >> 1;
  const int wn = wave & 1;
  const int n15 = lane & 15;
  const int quad = lane >> 4;
  const int srow = lane >> 2;
  const int cpl = (lane & 3) ^ (srow >> 2);

  const float* ao1 = aoacc + (size_t)B1 * DMODEL;
  const float* la1 = lacc + (size_t)B1 * NH;

  floatx4 acc[4][4];
#pragma unroll
  for (int i = 0; i < 4; ++i)
#pragma unroll
    for (int j = 0; j < 4; ++j) acc[i][j] = (floatx4){0.f, 0.f, 0.f, 0.f};

  for (int k0 = 0; k0 < DMODEL; k0 += 32) {
    __syncthreads();
#pragma unroll
    for (int jj = 0; jj < 2; ++jj) {
      const int j = wave * 2 + jj;
      const int row = j * 16 + srow;
      // A: load 8 f32 from each slab, sum, normalize, convert, ds_write 16B
      const size_t ga = (size_t)(m0 + row) * DMODEL + k0 + cpl * 8;
      const float4 a0 = *(const float4*)&aoacc[ga];
      const float4 a1 = *(const float4*)&aoacc[ga + 4];
      const float4 b0 = *(const float4*)&ao1[ga];
      const float4 b1 = *(const float4*)&ao1[ga + 4];
      const int head = (k0 + cpl * 8) >> 6;
      const float lsum = lacc[(m0 + row) * NH + head] + la1[(m0 + row) * NH + head];
      const float inv = 1.0f / lsum;
      ushort8 ah = {f2bf((a0.x + b0.x) * inv), f2bf((a0.y + b0.y) * inv),
                    f2bf((a0.z + b0.z) * inv), f2bf((a0.w + b0.w) * inv),
                    f2bf((a1.x + b1.x) * inv), f2bf((a1.y + b1.y) * inv),
                    f2bf((a1.z + b1.z) * inv), f2bf((a1.w + b1.w) * inv)};
      *(ushort8*)&sAh[j * 512 + lane * 8] = ah;
      // B: async staging
      gload16(Woh + (size_t)(n0 + row) * DMODEL + k0 + cpl * 8, &sBh[j * 512]);
    }
    __syncthreads();

    short8 afh[4];
#pragma unroll
    for (int mt = 0; mt < 4; ++mt) {
      const int row = wm * 64 + mt * 16 + n15;
      afh[mt] = *(const short8*)&sAh[row * 32 + ((quad ^ (n15 >> 2)) << 3)];
    }
#pragma unroll
    for (int nt = 0; nt < 4; ++nt) {
      const int row = wn * 64 + nt * 16 + n15;
      const short8 bfh = *(const short8*)&sBh[row * 32 + ((quad ^ (n15 >> 2)) << 3)];
#pragma unroll
      for (int mt = 0; mt < 4; ++mt)
        acc[mt][nt] = __builtin_amdgcn_mfma_f32_16x16x32_bf16(afh[mt], bfh, acc[mt][nt], 0, 0, 0);
    }
  }

#pragma unroll
  for (int mt = 0; mt < 4; ++mt)
#pragma unroll
    for (int nt = 0; nt < 4; ++nt)
#pragma unroll
      for (int rr = 0; rr < 4; ++rr) {
        const int row = m0 + wm * 64 + mt * 16 + quad * 4 + rr;
        const int col = n0 + wn * 64 + nt * 16 + n15;
        woout[(size_t)row * DMODEL + col] = acc[mt][nt][rr];
      }
}

// ---------------------------------------------------------------------------
__global__ __launch_bounds__(256) void l2norm_rows768_out(
    const float* __restrict__ x, float* __restrict__ out) {
  const int row = blockIdx.x;
  const float* xr = &x[(size_t)row * DMODEL];
  float ss = 0.0f;
  float vals[3];
#pragma unroll
  for (int i = 0; i < 3; ++i) {
    vals[i] = xr[threadIdx.x + i * 256];
    ss += vals[i] * vals[i];
  }
#pragma unroll
  for (int off = 32; off > 0; off >>= 1) ss += __shfl_xor(ss, off, 64);
  __shared__ float ws[4];
  if ((threadIdx.x & 63) == 0) ws[threadIdx.x >> 6] = ss;
  __syncthreads();
  const float tot = ws[0] + ws[1] + ws[2] + ws[3];
  const float sc = 1.0f / fmaxf(sqrtf(tot), 1e-12f);
  float* orow = &out[(size_t)row * DMODEL];
#pragma unroll
  for (int i = 0; i < 3; ++i) orow[threadIdx.x + i * 256] = vals[i] * sc;
}

// ---------------------------------------------------------------------------
extern "C" void kernel_launch(void* const* d_in, const int* in_sizes, int n_in,
                              void* d_out, int out_size, void* d_ws,
                              size_t ws_size, hipStream_t stream) {
  const float* x1 = (const float*)d_in[0];
  const float* x2 = (const float*)d_in[1];
  const float* Wq = (const float*)d_in[2];
  const float* Wk = (const float*)d_in[3];
  const float* Wv = (const float*)d_in[4];
  const float* Wo = (const float*)d_in[5];
  const int* invt = (const int*)d_in[6];
  float* outp = (float*)d_out;

  // workspace (bytes). Aliases are lifetime-safe under stream serialization:
  //  aoacc slab0 <- x1h/x1l region (dead after qk_proj)     [0,        6291456)
  //  aoacc slab1 <- x2h first half (dead after v_proj)      [6291456, 12582912)
  //  woout       <- x2h second half (dead after v_proj)     [12582912,18874368)
  //  vt_bf       <- x2l region (dead after qk_proj)         [18874368,31457280)
  //  lacc slabs  <- Wql region (dead after qk_proj)         [32636928,32833536)
  char* ws = (char*)d_ws;
  unsigned short* x1h = (unsigned short*)(ws + 0);
  unsigned short* x1l = (unsigned short*)(ws + 3145728);
  unsigned short* x2h = (unsigned short*)(ws + 6291456);
  unsigned short* x2l = (unsigned short*)(ws + 18874368);
  unsigned short* Wqh = (unsigned short*)(ws + 31457280);
  unsigned short* Wql = (unsigned short*)(ws + 32636928);
  unsigned short* Wkh = (unsigned short*)(ws + 33816576);
  unsigned short* Wkl = (unsigned short*)(ws + 34996224);
  unsigned short* Wvh = (unsigned short*)(ws + 36175872);
  unsigned short* Woh = (unsigned short*)(ws + 37355520);
  unsigned short* q_bf = (unsigned short*)(ws + 38535168);
  unsigned short* k_bf = (unsigned short*)(ws + 41680896);   // end 54263808
  // aliases:
  float* aoacc = (float*)(ws + 0);                  // 2 slabs, 12582912 B
  float* lacc = (float*)(ws + 32636928);            // 2 slabs, 196608 B
  unsigned short* vt_bf = (unsigned short*)(ws + 18874368);
  float* woout = (float*)(ws + 12582912);

  // 1) all prep in one launch
  prep_all<<<9984, 256, 0, stream>>>(x1, x1h, x1l, x2, x2h, x2l, Wq, Wqh, Wql,
                                     Wk, Wkh, Wkl, Wv, Wvh, Wo, Woh);
  // 2) q-proj + k-proj fused (split precision + per-head l2norm)
  qk_proj<<<480, 256, 0, stream>>>(x1h, x1l, Wqh, Wql, x2h, x2l, Wkh, Wkl,
                                   q_bf, k_bf);
  // 3) v-proj
  v_proj<<<384, 256, 0, stream>>>(Wvh, x2h, vt_bf);
  // 4) attention (R0 K-pipeline, V-direct, slab stores, XCD swizzle)
  attn_mfma<<<768, 256, 0, stream>>>(q_bf, k_bf, vt_bf, aoacc, lacc, invt);
  // 5) Wo projection with fused slab-sum + ao-normalize staging
  wo_proj<<<96, 256, 0, stream>>>(aoacc, lacc, Woh, woout);
  // 6) final row l2norm
  l2norm_rows768_out<<<B1, 256, 0, stream>>>(woout, outp);
}